// Round 10
// baseline (4006.212 us; speedup 1.0000x reference)
//
#include <hip/hip_runtime.h>
#include <hip/hip_bf16.h>
#include <stdint.h>
#include <stddef.h>

// NeuralODE y'=MLP(y), dopri 6-stage RK, 240 sequential MLP evals.
// Round 10 = r9 with the ring deepened 4 -> 8 slots (r9 post-mortem: ~10% of
// weight chunks served at L3 latency ~650cy; depth-4 = ~400cy cover -> stall.
// Depth-8 = ~700+cy cover -> latency-insensitive, port-bound).
// 64 chunks/eval, 64%8==0 -> slot = chunk&7, phase repeats every eval, ring
// runs continuously across evals and lgkm-only barriers. vmcnt(6)/(7) counted
// waits (never 0 in-loop); slot WAR closed by free lgkmcnt(0) after MFMAs.
// LDS squeeze: h1/h2 share one sH buffer (extra reads-done barrier before the
// h2 write). Total static LDS 161280 B of 163840.

typedef __bf16 bf16x8 __attribute__((ext_vector_type(8)));
typedef __bf16 bf16x4 __attribute__((ext_vector_type(4)));
typedef float  f32x4  __attribute__((ext_vector_type(4)));

#define DD 256
#define HH 512
#define RA 264   // sA row stride 528B  (132 dw = 4 mod 32 banks: 2-way, free)
#define RH 520   // sH row stride 1040B (260 dw = 4 mod 32 banks: 2-way, free)

#define W1P_OFF 0
#define W2P_OFF 131072            // 512*256
#define W3P_OFF (131072+262144)   // + 512*512

#define MFMA(A,B,C) __builtin_amdgcn_mfma_f32_16x16x32_bf16((A),(B),(C),0,0,0)
#define VMWAIT(N) asm volatile("s_waitcnt vmcnt(" #N ")" ::: "memory")
#define LGKM0()   asm volatile("s_waitcnt lgkmcnt(0)" ::: "memory")

// Swizzle: Wp[(t*KB + kb)*64 + lane][8] = W[t*16 + (lane&15)][kb*32 + (lane>>4)*8 ..+8]
// -> every 1KB chunk is lane-contiguous: exactly global_load_lds's linear layout.
__global__ void cvt_w(const float* __restrict__ W1, const float* __restrict__ W2,
                      const float* __restrict__ W3, __bf16* __restrict__ o)
{
    int i = blockIdx.x * blockDim.x + threadIdx.x;   // 0..65535
    const float* src;
    __bf16* dst;
    if (i < 16384) {              // W1: 32 tiles x 8 kb x 64 lanes
        int c = i, lane = c & 63, kb = (c >> 6) & 7, t = c >> 9;
        src = W1 + (size_t)(t*16 + (lane & 15))*DD + kb*32 + (lane >> 4)*8;
        dst = o + W1P_OFF + (size_t)c*8;
    } else if (i < 49152) {       // W2: 32 tiles x 16 kb x 64 lanes
        int c = i - 16384, lane = c & 63, kb = (c >> 6) & 15, t = c >> 10;
        src = W2 + (size_t)(t*16 + (lane & 15))*HH + kb*32 + (lane >> 4)*8;
        dst = o + W2P_OFF + (size_t)c*8;
    } else {                      // W3: 16 tiles x 16 kb x 64 lanes
        int c = i - 49152, lane = c & 63, kb = (c >> 6) & 15, t = c >> 10;
        src = W3 + (size_t)(t*16 + (lane & 15))*HH + kb*32 + (lane >> 4)*8;
        dst = o + W3P_OFF + (size_t)c*8;
    }
#pragma unroll
    for (int e = 0; e < 8; ++e) dst[e] = (__bf16)src[e];
}

// LDS-only barrier: in-flight global_load_lds (vmcnt) survives it.
__device__ __forceinline__ void wg_barrier() {
    asm volatile("s_waitcnt lgkmcnt(0)" ::: "memory");
    __builtin_amdgcn_s_barrier();
    asm volatile("" ::: "memory");
}

// global -> LDS direct DMA, 16B/lane = 1KB/wave (wave-uniform LDS base + lane*16).
typedef __attribute__((address_space(3))) uint32_t       lds_u32;
typedef const __attribute__((address_space(1))) uint32_t g_u32;
__device__ __forceinline__ void dma16(const __bf16* g, __bf16* l) {
    __builtin_amdgcn_global_load_lds((g_u32*)(uintptr_t)g,
                                     (lds_u32*)(uint32_t)(uintptr_t)l, 16, 0, 0);
}

// chunk index c (0..63, per-eval order) -> element offset in Wp for wave w:
//  c 0..15 : L1, t=c&1, kb=c>>1
//  c 16..47: L2, t=(c-16)&1, kb=(c-16)>>1
//  c 48..63: L3, kb=c-48
__device__ __forceinline__ int chunk_off(int w, int c) {
    if (c < 16) return w*8192 + (c&1)*4096 + (c>>1)*512;
    if (c < 48) return W2P_OFF + w*16384 + ((c-16)&1)*8192 + ((c-16)>>1)*512;
    return W3P_OFF + w*8192 + (c-48)*512;
}

__global__ __launch_bounds__(1024) __attribute__((amdgpu_waves_per_eu(4, 4)))
void ode_kernel(const float* __restrict__ x0, const int* __restrict__ Tp,
                const __bf16* __restrict__ Wp,
                const float* __restrict__ b1, const float* __restrict__ b2,
                const float* __restrict__ b3, float* __restrict__ out)
{
    __shared__ __bf16 sA[16 * RA];          // y_stage [16][256]         8448 B
    __shared__ __bf16 sH[16 * RH];          // h1 THEN h2 [16][512]     16640 B
    __shared__ __bf16 stage[16 * 8 * 512];  // 8-slot x 1KB ring/wave  131072 B
    __shared__ float  sb1[HH], sb2[HH], sb3[DD];                     // 5120 B

    const int   nT = *Tp - 1;
    const float hs = 10.0f / (float)nT * 0.25f;

    const int tid  = threadIdx.x;
    const int w    = tid >> 6;    // wave: neurons [w*32,+32) L1/L2, dims [w*16,+16) L3
    const int lane = tid & 63;
    const int lr   = lane & 15;
    const int lg   = lane >> 4;
    const int brow = blockIdx.x * 16 + lr;

    const __bf16* wpl  = Wp + lane * 8;          // per-lane global base
    __bf16*       ring = stage + w * 8 * 512;    // wave-uniform ring base
    const __bf16* rgl  = ring + lane * 8;        // per-lane ring read base

    auto dma = [&](int c) {                      // c may be >=64 (wraps to next eval)
        dma16(wpl + chunk_off(w, c & 63), ring + (c & 7) * 512);
    };

    if (tid < HH) { sb1[tid] = b1[tid]; sb2[tid] = b2[tid]; }
    if (tid < DD) { sb3[tid] = b3[tid]; }

    // RK state: lane holds dims [w*16+lg*4, +4) of batch row lr
    f32x4 yy = *(const f32x4*)(x0 + (size_t)brow * DD + w*16 + lg*4);
    f32x4 k1, k2, k3, k4, k5, k6;

    __bf16*       sAw = sA + lr*RA + w*16 + lg*4;
    __bf16*       sHw = sH + lr*RH + w*32 + lg*4;
    const __bf16* apA = sA + lr*RA + lg*8;
    const __bf16* apH = sH + lr*RH + lg*8;

    // ---- ring prologue: fill all 8 slots (chunks 0..7 of eval 0) ----
    dma(0); dma(1); dma(2); dma(3); dma(4); dma(5); dma(6); dma(7);

    auto store_stage = [&](f32x4 v) {
        bf16x4 o;
#pragma unroll
        for (int j = 0; j < 4; ++j) o[j] = (__bf16)v[j];
        *(bf16x4*)sAw = o;
    };

    auto mlp = [&](f32x4& kout) {
        wg_barrier();                              // A: sA ready (lgkm only)
        // ======== L1: K=256, tiles t0,t1 (chunks 0..15) ========
        f32x4 a0 = *(const f32x4*)(sb1 + w*32 + lg*4);
        f32x4 a1 = *(const f32x4*)(sb1 + w*32 + 16 + lg*4);
#pragma unroll
        for (int kb = 0; kb < 8; ++kb) {
            const int c0 = 2*kb;
            VMWAIT(6);                             // 2 oldest (c0,c0+1) landed
            bf16x8 b   = *(const bf16x8*)(apA + kb*32);
            bf16x8 wa0 = *(const bf16x8*)(rgl + ((c0    ) & 7)*512);
            bf16x8 wa1 = *(const bf16x8*)(rgl + ((c0 + 1) & 7)*512);
            a0 = MFMA(wa0, b, a0);
            a1 = MFMA(wa1, b, a1);
            LGKM0();                               // slot reads retired (free)
            dma(c0 + 8); dma(c0 + 9);              // refill, distance 8
        }
        {
            bf16x4 v0, v1;
#pragma unroll
            for (int j = 0; j < 4; ++j) {
                v0[j] = (__bf16)fmaxf(a0[j], 0.0f);
                v1[j] = (__bf16)fmaxf(a1[j], 0.0f);
            }
            *(bf16x4*)sHw        = v0;             // h1 -> sH
            *(bf16x4*)(sHw + 16) = v1;
        }
        wg_barrier();                              // B: h1 ready
        // ======== L2: K=512, tiles t0,t1 (chunks 16..47) ========
        a0 = *(const f32x4*)(sb2 + w*32 + lg*4);
        a1 = *(const f32x4*)(sb2 + w*32 + 16 + lg*4);
#pragma unroll
        for (int kb = 0; kb < 16; ++kb) {
            const int c0 = 16 + 2*kb;
            VMWAIT(6);
            bf16x8 b   = *(const bf16x8*)(apH + kb*32);
            bf16x8 wa0 = *(const bf16x8*)(rgl + ((c0    ) & 7)*512);
            bf16x8 wa1 = *(const bf16x8*)(rgl + ((c0 + 1) & 7)*512);
            a0 = MFMA(wa0, b, a0);
            a1 = MFMA(wa1, b, a1);
            LGKM0();
            dma(c0 + 8); dma(c0 + 9);
        }
        wg_barrier();                              // C: all h1 reads done
        {
            bf16x4 v0, v1;
#pragma unroll
            for (int j = 0; j < 4; ++j) {
                v0[j] = (__bf16)fmaxf(a0[j], 0.0f);
                v1[j] = (__bf16)fmaxf(a1[j], 0.0f);
            }
            *(bf16x4*)sHw        = v0;             // h2 -> sH (same buffer)
            *(bf16x4*)(sHw + 16) = v1;
        }
        wg_barrier();                              // D: h2 ready
        // ======== L3: K=512, 1 tile (chunks 48..63) ========
        f32x4 a = *(const f32x4*)(sb3 + w*16 + lg*4);
#pragma unroll
        for (int kb = 0; kb < 16; ++kb) {
            const int c = 48 + kb;
            VMWAIT(7);                             // oldest landed
            bf16x8 b  = *(const bf16x8*)(apH + kb*32);
            bf16x8 wa = *(const bf16x8*)(rgl + (c & 7)*512);
            a = MFMA(wa, b, a);
            LGKM0();
            dma(c + 8);                            // c>=56 wraps: next eval's L1
        }
        kout = a;
    };

    for (int t = 0; t < nT; ++t) {
        for (int ss = 0; ss < 4; ++ss) {
            store_stage(yy);
            mlp(k1);

            store_stage(yy + hs * (0.2f * k1));
            mlp(k2);

            store_stage(yy + hs * ((3.0f/40.0f)*k1 + (9.0f/40.0f)*k2));
            mlp(k3);

            store_stage(yy + hs * ((float)(44.0/45.0)*k1 - (float)(56.0/15.0)*k2
                                  + (float)(32.0/9.0)*k3));
            mlp(k4);

            store_stage(yy + hs * ((float)(19372.0/6561.0)*k1 - (float)(25360.0/2187.0)*k2
                                  + (float)(64448.0/6561.0)*k3 - (float)(212.0/729.0)*k4));
            mlp(k5);

            store_stage(yy + hs * ((float)(9017.0/3168.0)*k1 - (float)(355.0/33.0)*k2
                                  + (float)(46732.0/5247.0)*k3 + (float)(49.0/176.0)*k4
                                  - (float)(5103.0/18656.0)*k5));
            mlp(k6);

            yy = yy + hs * ((float)(35.0/384.0)*k1 + (float)(500.0/1113.0)*k3
                           + (float)(125.0/192.0)*k4 + (float)(-2187.0/6784.0)*k5
                           + (float)(11.0/84.0)*k6);
        }
        *(f32x4*)(out + ((size_t)brow * nT + t) * DD + w*16 + lg*4) = yy;
    }
    VMWAIT(0);   // retire trailing ring DMAs + out stores before endpgm
}

extern "C" void kernel_launch(void* const* d_in, const int* in_sizes, int n_in,
                              void* d_out, int out_size, void* d_ws, size_t ws_size,
                              hipStream_t stream)
{
    const float* x0 = (const float*)d_in[0];
    const int*   Tp = (const int*)  d_in[1];
    const float* W1 = (const float*)d_in[2];
    const float* b1 = (const float*)d_in[3];
    const float* W2 = (const float*)d_in[4];
    const float* b2 = (const float*)d_in[5];
    const float* W3 = (const float*)d_in[6];
    const float* b3 = (const float*)d_in[7];

    const int B = in_sizes[0] / DD;      // 1024

    __bf16* wb = (__bf16*)d_ws;          // 1 MiB swizzled bf16 weights
    cvt_w<<<256, 256, 0, stream>>>(W1, W2, W3, wb);

    ode_kernel<<<B / 16, 1024, 0, stream>>>(x0, Tp, wb, b1, b2, b3, (float*)d_out);
}